// Round 4
// baseline (230.997 us; speedup 1.0000x reference)
//
#include <hip/hip_runtime.h>

#define HID 32
#define MIN_WEIGHT -100000.0f

// ---------------------------------------------------------------------------
// Node-stage kernel.  Block = 256 threads = 4 waves x 64 lanes.
// Phase A: wave w computes a full 32-col partial acc over K-quarter w for the
//          64 nodes (lane = node). Row elements are loaded exactly once.
// Phase B: reduce 4 partials via LDS [4][64][33] (pad 33 -> conflict-free),
//          relu, write g back into the [0] slab (thread-owned cells).
// Phase C: oct-split projections o0 = g@P0 (and o1 = g@P1 if TWO), W/P
//          addresses wave-uniform -> scalar loads.
template <int ROW, bool TWO>
__global__ __launch_bounds__(256) void nodek(
    const float* __restrict__ emb, const int* __restrict__ n_map,
    const int* __restrict__ sel, const float* __restrict__ W,
    const float* __restrict__ P0, const float* __restrict__ P1,
    float* __restrict__ o0, float* __restrict__ o1, int n) {
    constexpr int KW = ROW / 4;       // K elements per wave
    __shared__ float lds[4 * 64 * 33];

    const int tid = threadIdx.x;
    const int w = __builtin_amdgcn_readfirstlane(tid >> 6);  // wave id
    const int l = tid & 63;                                  // node-in-block

    const int node = blockIdx.x * 64 + l;
    const bool valid = node < n;
    const int cn = valid ? node : n - 1;  // clamp: keep all lanes active
    const int local = sel ? sel[cn] : cn;
    const int gn = n_map[local];

    // ---- phase A: partial GEMM over my K quarter ---------------------------
    float acc[HID];
#pragma unroll
    for (int k = 0; k < HID; ++k) acc[k] = 0.f;

    const float* rowp = emb + (size_t)gn * ROW + w * KW;
    const float* Wp = W + (size_t)(w * KW) * HID;
#pragma unroll 2
    for (int j = 0; j < KW; j += 4) {
        float4 r4 = *(const float4*)(rowp + j);  // per-lane gather, 16B
        const float* w0 = Wp + (size_t)(j + 0) * HID;
        const float* w1 = Wp + (size_t)(j + 1) * HID;
        const float* w2 = Wp + (size_t)(j + 2) * HID;
        const float* w3 = Wp + (size_t)(j + 3) * HID;
#pragma unroll
        for (int k = 0; k < HID; ++k) acc[k] = fmaf(r4.x, w0[k], acc[k]);
#pragma unroll
        for (int k = 0; k < HID; ++k) acc[k] = fmaf(r4.y, w1[k], acc[k]);
#pragma unroll
        for (int k = 0; k < HID; ++k) acc[k] = fmaf(r4.z, w2[k], acc[k]);
#pragma unroll
        for (int k = 0; k < HID; ++k) acc[k] = fmaf(r4.w, w3[k], acc[k]);
    }

    // write partials: bank = (l + k) % 32 -> 2-way aliasing (free)
    {
        const int base = (w * 64 + l) * 33;
#pragma unroll
        for (int k = 0; k < HID; ++k) lds[base + k] = acc[k];
    }
    __syncthreads();

    // ---- phase B: reduce partials + relu; w acts as oct --------------------
    // thread (w,l) owns cols [w*8, w*8+8) of node l; reads its own part[0]
    // cells then overwrites them with g -> no barrier needed in between.
    float g8[8];
#pragma unroll
    for (int t = 0; t < 8; ++t) {
        const int c = w * 8 + t;
        float s = lds[(0 * 64 + l) * 33 + c] + lds[(1 * 64 + l) * 33 + c] +
                  lds[(2 * 64 + l) * 33 + c] + lds[(3 * 64 + l) * 33 + c];
        g8[t] = fmaxf(s, 0.f);
    }
#pragma unroll
    for (int t = 0; t < 8; ++t) lds[l * 33 + w * 8 + t] = g8[t];
    __syncthreads();

    // ---- phase C: projections (oct-split), g broadcast from LDS ------------
    float p0[8], p1[8];
#pragma unroll
    for (int t = 0; t < 8; ++t) { p0[t] = 0.f; p1[t] = 0.f; }
    const float* P0o = P0 + w * 8;
    const float* P1o = TWO ? (P1 + w * 8) : P0o;
    const int gbase = l * 33;
#pragma unroll 8
    for (int j = 0; j < HID; ++j) {
        float gv = lds[gbase + j];  // (l+j)%32 bank -> 2-way, free
        const float* pr0 = P0o + j * HID;
#pragma unroll
        for (int t = 0; t < 8; ++t) p0[t] = fmaf(gv, pr0[t], p0[t]);
        if (TWO) {
            const float* pr1 = P1o + j * HID;
#pragma unroll
            for (int t = 0; t < 8; ++t) p1[t] = fmaf(gv, pr1[t], p1[t]);
        }
    }

    if (valid) {
        float* d0 = o0 + (size_t)node * HID + w * 8;
        float4 v0a = {p0[0], p0[1], p0[2], p0[3]};
        float4 v0b = {p0[4], p0[5], p0[6], p0[7]};
        *(float4*)(d0 + 0) = v0a;
        *(float4*)(d0 + 4) = v0b;
        if (TWO) {
            float* d1 = o1 + (size_t)node * HID + w * 8;
            float4 v1a = {p1[0], p1[1], p1[2], p1[3]};
            float4 v1b = {p1[4], p1[5], p1[6], p1[7]};
            *(float4*)(d1 + 0) = v1a;
            *(float4*)(d1 + 4) = v1b;
        }
    }
}

// ---------------------------------------------------------------------------
// Per-edge: att = relu(SA[src] + DB[dst] + t2[batch] + be1) @ We2 + be2
// Writes att to its own slab and MIN_WEIGHT to the other slab (the two hop
// index sets partition [0,E), so the two edge launches cover all of d_out).
__global__ __launch_bounds__(256) void edge_kernel(
    const int* __restrict__ hop_idx, int n_e, const int* __restrict__ src,
    const int* __restrict__ dst, const int* __restrict__ e_batch,
    const float* __restrict__ SA, const float* __restrict__ DB,
    const float* __restrict__ t2, const float* __restrict__ be1,
    const float* __restrict__ We2, const float* __restrict__ be2,
    float* __restrict__ out_att, float* __restrict__ out_min) {
    int i = blockIdx.x * blockDim.x + threadIdx.x;
    if (i >= n_e) return;
    int e = hop_idx[i];
    const float* sv = SA + (size_t)src[e] * HID;
    const float* dv = DB + (size_t)dst[e] * HID;
    const float* tv = t2 + (size_t)e_batch[e] * HID;
    float att = be2[0];
#pragma unroll
    for (int k = 0; k < HID; k += 4) {
        float4 s4 = *(const float4*)(sv + k);
        float4 d4 = *(const float4*)(dv + k);
        float4 t4 = *(const float4*)(tv + k);
        float h;
        h = fmaxf(s4.x + d4.x + t4.x + be1[k + 0], 0.f); att = fmaf(h, We2[k + 0], att);
        h = fmaxf(s4.y + d4.y + t4.y + be1[k + 1], 0.f); att = fmaf(h, We2[k + 1], att);
        h = fmaxf(s4.z + d4.z + t4.z + be1[k + 2], 0.f); att = fmaf(h, We2[k + 2], att);
        h = fmaxf(s4.w + d4.w + t4.w + be1[k + 3], 0.f); att = fmaf(h, We2[k + 3], att);
    }
    out_att[e] = att;
    out_min[e] = MIN_WEIGHT;
}

// ---------------------------------------------------------------------------
extern "C" void kernel_launch(void* const* d_in, const int* in_sizes, int n_in,
                              void* d_out, int out_size, void* d_ws, size_t ws_size,
                              hipStream_t stream) {
    const float* emb0 = (const float*)d_in[0];
    const float* emb1 = (const float*)d_in[1];
    const float* emb2 = (const float*)d_in[2];
    const int* n_map = (const int*)d_in[3];
    const int* src = (const int*)d_in[4];
    const int* dst = (const int*)d_in[5];
    const int* e_batch = (const int*)d_in[6];
    const int* offset_node = (const int*)d_in[7];
    const int* one_hop = (const int*)d_in[8];
    const int* two_hop = (const int*)d_in[9];
    const float* W0 = (const float*)d_in[10];
    const float* W1 = (const float*)d_in[11];
    const float* W2 = (const float*)d_in[12];
    const float* We1 = (const float*)d_in[13];
    const float* be1 = (const float*)d_in[14];
    const float* We2 = (const float*)d_in[15];
    const float* be2 = (const float*)d_in[16];

    const int n_nodes = in_sizes[3];
    const int E = in_sizes[4];
    const int batch = in_sizes[7];
    const int H1 = in_sizes[8];  // one-hop edge count
    const int H2 = in_sizes[9];  // two-hop edge count

    float* out = (float*)d_out;

    const float* A = We1;             // rows 0..31   (multiplies s)
    const float* B = We1 + 32 * HID;  // rows 32..63  (multiplies d)
    const float* T = We1 + 64 * HID;  // rows 64..95  (multiplies t)

    // workspace layout: a0 | a1 | b1 | b2 | t2
    float* a0 = (float*)d_ws;
    float* a1 = a0 + (size_t)n_nodes * HID;
    float* b1 = a1 + (size_t)n_nodes * HID;
    float* b2 = b1 + (size_t)n_nodes * HID;
    float* t2 = b2 + (size_t)n_nodes * HID;

    const int nblk = (n_nodes + 63) / 64;
    // a0 = relu(emb0@W0)@A
    nodek<128, false><<<nblk, 256, 0, stream>>>(
        emb0, n_map, nullptr, W0, A, nullptr, a0, nullptr, n_nodes);
    // a1 = relu(emb1@W1)@A ; b1 = relu(emb1@W1)@B
    nodek<256, true><<<nblk, 256, 0, stream>>>(
        emb1, n_map, nullptr, W1, A, B, a1, b1, n_nodes);
    // b2 = relu(emb2@W2)@B
    nodek<64, false><<<nblk, 256, 0, stream>>>(
        emb2, n_map, nullptr, W2, B, nullptr, b2, nullptr, n_nodes);
    // t2 = relu(emb2[n_map[offset_node]]@W2)@T
    nodek<64, false><<<(batch + 63) / 64, 256, 0, stream>>>(
        emb2, n_map, offset_node, W2, T, nullptr, t2, nullptr, batch);

    // one-hop edges: att -> slab 1, MIN -> slab 0 (src via W1@A, dst via W2@B)
    edge_kernel<<<(H1 + 255) / 256, 256, 0, stream>>>(
        one_hop, H1, src, dst, e_batch, a1, b2, t2, be1, We2, be2,
        out + (size_t)E, out);
    // two-hop edges: att -> slab 0, MIN -> slab 1 (src via W0@A, dst via W1@B)
    edge_kernel<<<(H2 + 255) / 256, 256, 0, stream>>>(
        two_hop, H2, src, dst, e_batch, a0, b1, t2, be1, We2, be2,
        out, out + (size_t)E);
}